// Round 11
// baseline (970.909 us; speedup 1.0000x reference)
//
#include <hip/hip_runtime.h>
#include <hip/hip_cooperative_groups.h>

#define FDIM 128

namespace cg = cooperative_groups;

typedef __attribute__((ext_vector_type(8))) short bf16x8;
typedef __attribute__((ext_vector_type(4))) float f32x4;
typedef __attribute__((ext_vector_type(2))) float f32x2;

__device__ __forceinline__ unsigned int cvt_bf16(float f) {
    unsigned int u = __float_as_uint(f);
    return (u + 0x7fffu + ((u >> 16) & 1u)) >> 16;   // RNE
}

// bf16 packed layout (GEMM in/out): row of 64 uints; uint u = (feat u, feat u+64).
// fp8 gather layout: row of 64 ushorts (128 B); ushort u = e4m3 pair (feat u, feat u+64),
// value = dis[row] * hw[row][feat]. Row n = zeros (padded-gather target).

// ---------------- GEMM phase: g8[n][64u] = fp8(dis[m] * (A @ W)) ----------------

__device__ __forceinline__ void gemm_phase(const unsigned* __restrict__ A16,
                                           const float* __restrict__ A32,
                                           const unsigned* __restrict__ Bt16,
                                           const float* __restrict__ dis,
                                           unsigned short* __restrict__ g8, int n) {
    int tid = threadIdx.x;
    int wave = tid >> 6, lane = tid & 63;
    int quad = lane >> 4, r16 = lane & 15;
    int nT = (n + 127) >> 7;                       // 128 rows per block-iteration
    for (int T = blockIdx.x; T < nT; T += gridDim.x) {
        int m0 = T * 128 + wave * 16;
        if (m0 >= n) continue;
        f32x4 acc[8] = {};
        #pragma unroll
        for (int ks = 0; ks < 4; ks++) {
            int m = m0 + r16;
            if (m >= n) m = n - 1;
            int u0 = ks * 16 + quad * 4;
            bf16x8 af;
            if (A32) {
                float4 lo = *(const float4*)(A32 + (size_t)m * 128 + u0);
                float4 hi = *(const float4*)(A32 + (size_t)m * 128 + u0 + 64);
                uint4 p;
                p.x = cvt_bf16(lo.x) | (cvt_bf16(hi.x) << 16);
                p.y = cvt_bf16(lo.y) | (cvt_bf16(hi.y) << 16);
                p.z = cvt_bf16(lo.z) | (cvt_bf16(hi.z) << 16);
                p.w = cvt_bf16(lo.w) | (cvt_bf16(hi.w) << 16);
                af = *(bf16x8*)&p;
            } else {
                uint4 av = *(const uint4*)(A16 + (size_t)m * 64 + u0);
                af = *(bf16x8*)&av;
            }
            #pragma unroll
            for (int t = 0; t < 8; t++) {
                int ncol = t * 16 + r16;
                uint4 bv = *(const uint4*)(Bt16 + (size_t)ncol * 64 + u0);
                bf16x8 bf = *(bf16x8*)&bv;
                acc[t] = __builtin_amdgcn_mfma_f32_16x16x32_bf16(af, bf, acc[t], 0, 0, 0);
            }
        }
        #pragma unroll
        for (int r = 0; r < 4; r++) {
            int row = m0 + quad * 4 + r;
            if (row < n) {
                float dr = dis[row];
                #pragma unroll
                for (int t = 0; t < 4; t++) {
                    int p = __builtin_amdgcn_cvt_pk_fp8_f32(dr * acc[t][r], dr * acc[t + 4][r], 0, false);
                    g8[(size_t)row * 64 + t * 16 + r16] = (unsigned short)(p & 0xffff);
                }
            }
        }
    }
}

// ---------------- Aggregation phase (R7 body, block-stride) ----------------

#define AGG_ACC(v)                                                     \
    { f32x2 p;                                                         \
      p = __builtin_amdgcn_cvt_pk_f32_fp8((int)v.x, 0); f0[0]+=p.x; f1[0]+=p.y; \
      p = __builtin_amdgcn_cvt_pk_f32_fp8((int)v.x, 1); f0[1]+=p.x; f1[1]+=p.y; \
      p = __builtin_amdgcn_cvt_pk_f32_fp8((int)v.y, 0); f0[2]+=p.x; f1[2]+=p.y; \
      p = __builtin_amdgcn_cvt_pk_f32_fp8((int)v.y, 1); f0[3]+=p.x; f1[3]+=p.y; \
      p = __builtin_amdgcn_cvt_pk_f32_fp8((int)v.z, 0); f0[4]+=p.x; f1[4]+=p.y; \
      p = __builtin_amdgcn_cvt_pk_f32_fp8((int)v.z, 1); f0[5]+=p.x; f1[5]+=p.y; \
      p = __builtin_amdgcn_cvt_pk_f32_fp8((int)v.w, 0); f0[6]+=p.x; f1[6]+=p.y; \
      p = __builtin_amdgcn_cvt_pk_f32_fp8((int)v.w, 1); f0[7]+=p.x; f1[7]+=p.y; }

#define ISSUE1(buf, ereg, EBASE, mlim)                                 \
    { int e = (EBASE) + j;                                             \
      int s = __shfl(ereg, e);                                         \
      if (e >= (mlim)) s = n;                                          \
      buf = *(const uint4*)(g8 + (size_t)(unsigned)s * 64u + c * 8); }

#define ROUND4(ereg, Q0, mlim)                                         \
    { uint4 u0, u1, u2, u3;                                            \
      ISSUE1(u0, ereg, (Q0) + 0, mlim)                                 \
      if ((mlim) > (Q0) + 8)  ISSUE1(u1, ereg, (Q0) + 8,  mlim)        \
      if ((mlim) > (Q0) + 16) ISSUE1(u2, ereg, (Q0) + 16, mlim)        \
      if ((mlim) > (Q0) + 24) ISSUE1(u3, ereg, (Q0) + 24, mlim)        \
      AGG_ACC(u0)                                                      \
      if ((mlim) > (Q0) + 8)  AGG_ACC(u1)                              \
      if ((mlim) > (Q0) + 16) AGG_ACC(u2)                              \
      if ((mlim) > (Q0) + 24) AGG_ACC(u3) }

__device__ __forceinline__ void agg_phase(const unsigned short* __restrict__ g8,
                                          const float* __restrict__ dis,
                                          const int* __restrict__ rowptr,
                                          const int* __restrict__ csrs,
                                          const float* __restrict__ bias,
                                          unsigned* __restrict__ out16,   // may be null
                                          float* __restrict__ poolseg,
                                          float* lpool, int n) {
    int tid = threadIdx.x;
    if (tid < 128) lpool[tid] = 0.f;
    __syncthreads();

    int wave = tid >> 6, lane = tid & 63;
    int j = lane >> 3;       // edge slot
    int c = lane & 7;        // 16B chunk of the 128B row

    float b0[8], b1[8];
    *(float4*)&b0[0] = *(const float4*)(bias + c * 8);
    *(float4*)&b0[4] = *(const float4*)(bias + c * 8 + 4);
    *(float4*)&b1[0] = *(const float4*)(bias + 64 + c * 8);
    *(float4*)&b1[4] = *(const float4*)(bias + 64 + c * 8 + 4);

    float pp0[8] = {}, pp1[8] = {};
    int nA = (n + 31) >> 5;                      // 32 nodes per block-iteration
    for (int a = blockIdx.x; a < nA; a += gridDim.x) {
        int node0 = a * 32 + wave * 4;

        int rpv = 0; float dv = 0.f;
        if (lane <= 4) rpv = rowptr[min(node0 + lane, n)];
        if (lane < 4)  dv  = dis[min(node0 + lane, n - 1)];

        int er[4];
        #pragma unroll
        for (int i = 0; i < 4; i++) {
            int beg = __shfl(rpv, i);
            er[i] = csrs[beg + lane];            // csrs padded by 64
        }

        uint4 c0, c1, c2, c3, sB;
        {
            int deg = __shfl(rpv, 1) - __shfl(rpv, 0);
            int mlim = min(deg, 64);
            int ereg = er[0];
            ISSUE1(c0, ereg, 0, mlim)
            if (deg > 8)  ISSUE1(c1, ereg, 8,  mlim)
            if (deg > 16) ISSUE1(c2, ereg, 16, mlim)
            if (deg > 24) ISSUE1(c3, ereg, 24, mlim)
            int s = (node0 < n && j == 0) ? node0 : n;
            sB = *(const uint4*)(g8 + (size_t)(unsigned)s * 64u + c * 8);
        }

        #pragma unroll
        for (int i = 0; i < 4; i++) {
            int node = node0 + i;
            bool ok = node < n;
            int beg = __shfl(rpv, i);
            int end = __shfl(rpv, i + 1);
            int deg = end - beg;
            float di = __shfl(dv, i);

            float f0[8] = {}, f1[8] = {};
            AGG_ACC(c0)
            if (deg > 8)  AGG_ACC(c1)
            if (deg > 16) AGG_ACC(c2)
            if (deg > 24) AGG_ACC(c3)
            if (deg > 32) {
                int mlim = min(deg, 64);
                ROUND4(er[i], 32, mlim)
                for (int b2 = 64; b2 < deg; b2 += 64) {
                    int ereg2 = csrs[beg + b2 + lane];
                    int ml2 = min(deg - b2, 64);
                    ROUND4(ereg2, 0, ml2)
                    if (ml2 > 32) ROUND4(ereg2, 32, ml2)
                }
            }

            uint4 n0v, n1v, n2v, n3v, nS;
            if (i < 3) {
                int nd = __shfl(rpv, i + 2) - end;
                int nml = min(nd, 64);
                int ner = er[i + 1];
                ISSUE1(n0v, ner, 0, nml)
                if (nd > 8)  ISSUE1(n1v, ner, 8,  nml)
                if (nd > 16) ISSUE1(n2v, ner, 16, nml)
                if (nd > 24) ISSUE1(n3v, ner, 24, nml)
                int s = (node + 1 < n && j == 0) ? (node + 1) : n;
                nS = *(const uint4*)(g8 + (size_t)(unsigned)s * 64u + c * 8);
            }

            #pragma unroll
            for (int k = 0; k < 8; k++) {
                f0[k] += __shfl_xor(f0[k], 8);  f1[k] += __shfl_xor(f1[k], 8);
                f0[k] += __shfl_xor(f0[k], 16); f1[k] += __shfl_xor(f1[k], 16);
                f0[k] += __shfl_xor(f0[k], 32); f1[k] += __shfl_xor(f1[k], 32);
            }
            if (j == 0) AGG_ACC(sB)

            if (ok) {
                float r0[8], r1[8];
                #pragma unroll
                for (int k = 0; k < 8; k++) {
                    r0[k] = fmaxf(di * f0[k] + b0[k], 0.f);
                    r1[k] = fmaxf(di * f1[k] + b1[k], 0.f);
                    pp0[k] += r0[k];
                    pp1[k] += r1[k];
                }
                if (out16 && j == 0) {
                    uint4 wa, wb;
                    wa.x = cvt_bf16(r0[0]) | (cvt_bf16(r1[0]) << 16);
                    wa.y = cvt_bf16(r0[1]) | (cvt_bf16(r1[1]) << 16);
                    wa.z = cvt_bf16(r0[2]) | (cvt_bf16(r1[2]) << 16);
                    wa.w = cvt_bf16(r0[3]) | (cvt_bf16(r1[3]) << 16);
                    wb.x = cvt_bf16(r0[4]) | (cvt_bf16(r1[4]) << 16);
                    wb.y = cvt_bf16(r0[5]) | (cvt_bf16(r1[5]) << 16);
                    wb.z = cvt_bf16(r0[6]) | (cvt_bf16(r1[6]) << 16);
                    wb.w = cvt_bf16(r0[7]) | (cvt_bf16(r1[7]) << 16);
                    *(uint4*)(out16 + (size_t)node * 64 + c * 8)     = wa;
                    *(uint4*)(out16 + (size_t)node * 64 + c * 8 + 4) = wb;
                }
            }
            c0 = n0v; c1 = n1v; c2 = n2v; c3 = n3v; sB = nS;
        }
    }

    if (j == 0) {
        #pragma unroll
        for (int k = 0; k < 8; k++) {
            atomicAdd(&lpool[c * 8 + k],      pp0[k]);
            atomicAdd(&lpool[64 + c * 8 + k], pp1[k]);
        }
    }
    __syncthreads();
    if (tid < 128) atomicAdd(&poolseg[tid], lpool[tid]);
}

// ---------------- mega kernel: entire pipeline, one cooperative launch ----------

__global__ __launch_bounds__(512, 4) void mega_kernel(
    const float* __restrict__ x, const int* __restrict__ src, const int* __restrict__ tgt,
    const float* __restrict__ W1, const float* __restrict__ b1,
    const float* __restrict__ W2, const float* __restrict__ b2,
    const float* __restrict__ W3, const float* __restrict__ b3,
    const float* __restrict__ fw1, const float* __restrict__ fb1,
    const float* __restrict__ fw2, const float* __restrict__ fb2,
    const float* __restrict__ fw3, const float* __restrict__ fb3,
    float* __restrict__ out,
    unsigned* __restrict__ B1t, unsigned* __restrict__ B2t, unsigned* __restrict__ B3t,
    unsigned short* __restrict__ g8, unsigned* __restrict__ A2, unsigned* __restrict__ A3,
    float* __restrict__ dis, int* __restrict__ count, int* __restrict__ rowptr,
    int* __restrict__ cursor, int* __restrict__ csrs, float* __restrict__ pool,
    int* __restrict__ bsum, int* __restrict__ bpre,
    int n, int ne)
{
    cg::grid_group grid = cg::this_grid();
    const int tid = threadIdx.x;
    const int bid = blockIdx.x;
    const int G   = gridDim.x;
    const int gstride = G * 512;

    __shared__ int   sm[512];
    __shared__ float lpool[128];
    __shared__ float h0[384];
    __shared__ float h1[128];
    __shared__ float h2[64];

    // ---- P0: W packs + g8 zero row + count zero + pool zero ----
    {
        int total0 = 24640 + n + 384;   // 3*8192 Wpack + 64 zero-row + n + 384
        for (int i = bid * 512 + tid; i < total0; i += gstride) {
            if (i < 24576) {
                int w = i >> 13, jj = i & 8191;
                const float* W = (w == 0) ? W1 : (w == 1) ? W2 : W3;
                unsigned* B    = (w == 0) ? B1t : (w == 1) ? B2t : B3t;
                int nn = jj >> 6, u = jj & 63;
                float lo = W[(size_t)u * 128 + nn];
                float hi = W[(size_t)(u + 64) * 128 + nn];
                B[jj] = cvt_bf16(lo) | (cvt_bf16(hi) << 16);
            } else if (i < 24640) {
                g8[(size_t)n * 64 + (i - 24576)] = 0;
            } else if (i < 24640 + n) {
                count[i - 24640] = 0;
            } else {
                pool[i - 24640 - n] = 0.f;
            }
        }
    }
    grid.sync();

    // ---- P1: degree histogram ----
    for (int e = bid * 512 + tid; e < ne; e += gstride)
        atomicAdd(&count[tgt[e]], 1);
    grid.sync();

    // ---- P2a: per-block scan (one element per thread; requires G*512 >= n) ----
    int i_elem = bid * 512 + tid;
    int cval = (i_elem < n) ? count[i_elem] : 0;
    if (i_elem < n) dis[i_elem] = rsqrtf((float)(cval + 1));   // +1 self-loop
    sm[tid] = cval;
    __syncthreads();
    for (int off = 1; off < 512; off <<= 1) {
        int v = sm[tid];
        int u = (tid >= off) ? sm[tid - off] : 0;
        __syncthreads();
        sm[tid] = v + u;
        __syncthreads();
    }
    int epre = sm[tid] - cval;          // exclusive within block (persists in register)
    if (tid == 511) bsum[bid] = sm[511];
    grid.sync();

    // ---- P2b: block 0 scans block sums ----
    if (bid == 0) {
        int v = (tid < G) ? bsum[tid] : 0;
        sm[tid] = v;
        __syncthreads();
        for (int off = 1; off < 512; off <<= 1) {
            int a = sm[tid];
            int u = (tid >= off) ? sm[tid - off] : 0;
            __syncthreads();
            sm[tid] = a + u;
            __syncthreads();
        }
        bpre[tid] = sm[tid] - v;
        if (tid == 511) rowptr[n] = sm[511];
    }
    grid.sync();

    // ---- P2c: write rowptr + cursor ----
    if (i_elem < n) {
        int run = bpre[bid] + epre;
        rowptr[i_elem] = run;
        cursor[i_elem] = run;
    }
    grid.sync();

    // ---- P3: fill CSR ----
    for (int e = bid * 512 + tid; e < ne; e += gstride) {
        int t = tgt[e];
        int s = src[e];
        int slot = atomicAdd(&cursor[t], 1);
        csrs[slot] = s;
    }
    grid.sync();

    // ---- layer 1 ----
    gemm_phase(nullptr, x, B1t, dis, g8, n);
    grid.sync();
    agg_phase(g8, dis, rowptr, csrs, b1, A2, pool + 0, lpool, n);
    grid.sync();

    // ---- layer 2 ----
    gemm_phase(A2, nullptr, B2t, dis, g8, n);
    grid.sync();
    agg_phase(g8, dis, rowptr, csrs, b2, A3, pool + 128, lpool, n);
    grid.sync();

    // ---- layer 3 (no feature store) ----
    gemm_phase(A3, nullptr, B3t, dis, g8, n);
    grid.sync();
    agg_phase(g8, dis, rowptr, csrs, b3, (unsigned*)nullptr, pool + 256, lpool, n);
    grid.sync();

    // ---- MLP head (block 0) ----
    if (bid == 0) {
        if (tid < 384) h0[tid] = pool[tid];
        __syncthreads();
        if (tid < 128) {
            float s = fb1[tid];
            for (int k = 0; k < 384; k++) s += h0[k] * fw1[k * 128 + tid];
            h1[tid] = fmaxf(s, 0.f);
        }
        __syncthreads();
        if (tid < 64) {
            float s = fb2[tid];
            for (int k = 0; k < 128; k++) s += h1[k] * fw2[k * 64 + tid];
            h2[tid] = fmaxf(s, 0.f);
        }
        __syncthreads();
        if (tid < 10) {
            float s = fb3[tid];
            for (int k = 0; k < 64; k++) s += h2[k] * fw3[k * 10 + tid];
            out[tid] = s;
        }
    }
}

// ---------------- launch ----------------

extern "C" void kernel_launch(void* const* d_in, const int* in_sizes, int n_in,
                              void* d_out, int out_size, void* d_ws, size_t ws_size,
                              hipStream_t stream) {
    const float* x   = (const float*)d_in[0];
    const int*   ei  = (const int*)d_in[1];
    const float* W1  = (const float*)d_in[2];
    const float* b1  = (const float*)d_in[3];
    const float* W2  = (const float*)d_in[4];
    const float* b2  = (const float*)d_in[5];
    const float* W3  = (const float*)d_in[6];
    const float* b3  = (const float*)d_in[7];
    const float* fw1 = (const float*)d_in[8];
    const float* fb1 = (const float*)d_in[9];
    const float* fw2 = (const float*)d_in[10];
    const float* fb2 = (const float*)d_in[11];
    const float* fw3 = (const float*)d_in[12];
    const float* fb3 = (const float*)d_in[13];
    float* out = (float*)d_out;

    int n  = in_sizes[0] / FDIM;   // 50000
    int ne = in_sizes[1] / 2;      // 600000
    const int* src = ei;
    const int* tgt = ei + ne;

    char* ws = (char*)d_ws;
    size_t packBytes = (size_t)n * 64 * sizeof(unsigned);   // 12.8 MB
    unsigned* A2   = (unsigned*)ws;  ws += packBytes;
    unsigned* A3   = (unsigned*)ws;  ws += packBytes;
    unsigned short* g8 = (unsigned short*)ws; ws += (((size_t)(n + 1) * 64 * 2 + 127) / 128) * 128; // 6.4 MB
    unsigned* B1t  = (unsigned*)ws;  ws += 128 * 64 * 4;
    unsigned* B2t  = (unsigned*)ws;  ws += 128 * 64 * 4;
    unsigned* B3t  = (unsigned*)ws;  ws += 128 * 64 * 4;
    float* dis  = (float*)ws;        ws += (size_t)n * 4;
    int* count  = (int*)ws;          ws += (size_t)n * 4;
    int* rowptr = (int*)ws;          ws += ((size_t)(n + 4) * 4 / 16) * 16;
    int* cursor = (int*)ws;          ws += (size_t)n * 4;
    int* csrs   = (int*)ws;          ws += (size_t)(ne + 64) * 4;   // +64 pad for prefetch
    float* pool = (float*)ws;        ws += 384 * 4;
    int* bsum   = (int*)ws;          ws += 512 * 4;
    int* bpre   = (int*)ws;          ws += 512 * 4;

    // grid: all blocks co-resident (cooperative). 512 threads, target 2 blocks/CU.
    int maxPerCU = 0;
    hipError_t oe = hipOccupancyMaxActiveBlocksPerMultiprocessor(&maxPerCU, mega_kernel, 512, 0);
    int G = (oe == hipSuccess && maxPerCU > 0) ? maxPerCU * 256 : 256;
    if (G > 512) G = 512;
    if (G < 256) G = 256;     // 1 block/CU floor; also keeps G*512 >= n for the scan

    void* kargs[] = {
        (void*)&x, (void*)&src, (void*)&tgt,
        (void*)&W1, (void*)&b1, (void*)&W2, (void*)&b2, (void*)&W3, (void*)&b3,
        (void*)&fw1, (void*)&fb1, (void*)&fw2, (void*)&fb2, (void*)&fw3, (void*)&fb3,
        (void*)&out,
        (void*)&B1t, (void*)&B2t, (void*)&B3t,
        (void*)&g8, (void*)&A2, (void*)&A3,
        (void*)&dis, (void*)&count, (void*)&rowptr, (void*)&cursor, (void*)&csrs,
        (void*)&pool, (void*)&bsum, (void*)&bpre,
        (void*)&n, (void*)&ne
    };
    hipLaunchCooperativeKernel(mega_kernel, dim3(G), dim3(512), kargs, 0, stream);
}

// Round 12
// 460.827 us; speedup vs baseline: 2.1069x; 2.1069x over previous
//
#include <hip/hip_runtime.h>

#define FDIM 128

typedef __attribute__((ext_vector_type(8))) short bf16x8;
typedef __attribute__((ext_vector_type(4))) float f32x4;
typedef __attribute__((ext_vector_type(2))) float f32x2;

__device__ __forceinline__ unsigned int cvt_bf16(float f) {
    unsigned int u = __float_as_uint(f);
    return (u + 0x7fffu + ((u >> 16) & 1u)) >> 16;   // RNE
}

// bf16 packed layout (GEMM in/out): row of 64 uints; uint u = (feat u, feat u+64).
// fp8 gather layout: row of 64 ushorts (128 B); ushort u = e4m3 pair (feat u, feat u+64),
// value = dis[row] * hw[row][feat]. Row n = zeros (padded-gather target).
// ctrs: [0]=scan done-counter, [1]=scan flag, [2]=agg3 done-counter.

// ---------------- prep + hist (fused; count pre-zeroed by memset) ----------------

__global__ void prephist_kernel(const float* __restrict__ W1, const float* __restrict__ W2,
                                const float* __restrict__ W3,
                                unsigned* __restrict__ B1, unsigned* __restrict__ B2,
                                unsigned* __restrict__ B3,
                                unsigned short* __restrict__ g8,
                                const int* __restrict__ tgt, int* __restrict__ count,
                                int n, int ne) {
    int i = blockIdx.x * blockDim.x + threadIdx.x;
    if (i < 24576) {
        int w = i >> 13, jj = i & 8191;
        const float* W = (w == 0) ? W1 : (w == 1) ? W2 : W3;
        unsigned* B    = (w == 0) ? B1 : (w == 1) ? B2 : B3;
        int nn = jj >> 6, u = jj & 63;
        float lo = W[(size_t)u * 128 + nn];
        float hi = W[(size_t)(u + 64) * 128 + nn];
        B[jj] = cvt_bf16(lo) | (cvt_bf16(hi) << 16);
    } else if (i < 24640) {
        g8[(size_t)n * 64 + (i - 24576)] = 0;       // zero row for padded gathers
    } else {
        int e = i - 24640;
        if (e < ne) atomicAdd(&count[tgt[e]], 1);
    }
}

// ---------------- single-dispatch scan (25 blocks, last-block prefix) ------------

__global__ __launch_bounds__(256) void scan_kernel(const int* __restrict__ count,
                                                   float* __restrict__ dis,
                                                   int* __restrict__ rowptr,
                                                   int* __restrict__ cursor,
                                                   int* __restrict__ bsum,
                                                   int* __restrict__ bpre,
                                                   int* __restrict__ ctrs,
                                                   int n, int nb) {
    __shared__ int sm[256];
    __shared__ int sbase;
    int tid = threadIdx.x, blk = blockIdx.x;
    int base = blk * 2048 + tid * 8;
    int c[8];
    int s = 0;
    #pragma unroll
    for (int q = 0; q < 8; q++) {
        int i = base + q;
        c[q] = 0;
        if (i < n) {
            c[q] = count[i];
            s += c[q];
            dis[i] = rsqrtf((float)(c[q] + 1));     // +1 self-loop
        }
    }
    sm[tid] = s;
    __syncthreads();
    for (int off = 1; off < 256; off <<= 1) {
        int v = sm[tid];
        int u = (tid >= off) ? sm[tid - off] : 0;
        __syncthreads();
        sm[tid] = v + u;
        __syncthreads();
    }
    int tpre = sm[tid] - s;                         // exclusive within block
    int btot = sm[255];
    __syncthreads();                                // sm reuse below

    if (tid == 0) {
        __hip_atomic_store(&bsum[blk], btot, __ATOMIC_RELAXED, __HIP_MEMORY_SCOPE_AGENT);
        __threadfence();
        int old = atomicAdd(&ctrs[0], 1);
        if (old == nb - 1) {                        // last block: scan the block sums
            int run = 0;
            for (int b = 0; b < nb; b++) {
                int v = __hip_atomic_load(&bsum[b], __ATOMIC_RELAXED, __HIP_MEMORY_SCOPE_AGENT);
                __hip_atomic_store(&bpre[b], run, __ATOMIC_RELAXED, __HIP_MEMORY_SCOPE_AGENT);
                run += v;
            }
            rowptr[n] = run;
            __threadfence();
            __hip_atomic_store(&ctrs[1], 1, __ATOMIC_RELEASE, __HIP_MEMORY_SCOPE_AGENT);
        }
        while (__hip_atomic_load(&ctrs[1], __ATOMIC_ACQUIRE, __HIP_MEMORY_SCOPE_AGENT) == 0) {}
        sbase = __hip_atomic_load(&bpre[blk], __ATOMIC_RELAXED, __HIP_MEMORY_SCOPE_AGENT);
    }
    __syncthreads();
    int run = sbase + tpre;
    #pragma unroll
    for (int q = 0; q < 8; q++) {
        int i = base + q;
        if (i < n) {
            rowptr[i] = run;
            cursor[i] = run;
            run += c[q];
        }
    }
}

// ---------------- GEMM body (device fn; 512-thr variant used fused & standalone) --

__device__ __forceinline__ void gemm_body(const unsigned* __restrict__ A16,
                                          const float* __restrict__ A32,
                                          const unsigned* __restrict__ Bt16,
                                          const float* __restrict__ dis,
                                          unsigned short* __restrict__ g8,
                                          int n, int T) {
    int tid = threadIdx.x;
    int wave = tid >> 6, lane = tid & 63;
    int quad = lane >> 4, r16 = lane & 15;
    int m0 = T * 128 + wave * 16;
    if (m0 >= n) return;
    f32x4 acc[8] = {};
    #pragma unroll
    for (int ks = 0; ks < 4; ks++) {
        int m = m0 + r16;
        if (m >= n) m = n - 1;
        int u0 = ks * 16 + quad * 4;
        bf16x8 af;
        if (A32) {
            float4 lo = *(const float4*)(A32 + (size_t)m * 128 + u0);
            float4 hi = *(const float4*)(A32 + (size_t)m * 128 + u0 + 64);
            uint4 p;
            p.x = cvt_bf16(lo.x) | (cvt_bf16(hi.x) << 16);
            p.y = cvt_bf16(lo.y) | (cvt_bf16(hi.y) << 16);
            p.z = cvt_bf16(lo.z) | (cvt_bf16(hi.z) << 16);
            p.w = cvt_bf16(lo.w) | (cvt_bf16(hi.w) << 16);
            af = *(bf16x8*)&p;
        } else {
            uint4 av = *(const uint4*)(A16 + (size_t)m * 64 + u0);
            af = *(bf16x8*)&av;
        }
        #pragma unroll
        for (int t = 0; t < 8; t++) {
            int ncol = t * 16 + r16;
            uint4 bv = *(const uint4*)(Bt16 + (size_t)ncol * 64 + u0);
            bf16x8 bf = *(bf16x8*)&bv;
            acc[t] = __builtin_amdgcn_mfma_f32_16x16x32_bf16(af, bf, acc[t], 0, 0, 0);
        }
    }
    #pragma unroll
    for (int r = 0; r < 4; r++) {
        int row = m0 + quad * 4 + r;
        if (row < n) {
            float dr = dis[row];
            #pragma unroll
            for (int t = 0; t < 4; t++) {
                int p = __builtin_amdgcn_cvt_pk_fp8_f32(dr * acc[t][r], dr * acc[t + 4][r], 0, false);
                g8[(size_t)row * 64 + t * 16 + r16] = (unsigned short)(p & 0xffff);
            }
        }
    }
}

// ---------------- fill + gemm1 (fused, independent writes) ----------------

__global__ __launch_bounds__(512) void fillgemm_kernel(const int* __restrict__ src,
                                                       const int* __restrict__ tgt,
                                                       int* __restrict__ cursor,
                                                       int* __restrict__ csrs,
                                                       const float* __restrict__ x,
                                                       const unsigned* __restrict__ B1t,
                                                       const float* __restrict__ dis,
                                                       unsigned short* __restrict__ g8,
                                                       int n, int ne, int nG, int nF) {
    if ((int)blockIdx.x < nG) {
        gemm_body(nullptr, x, B1t, dis, g8, n, blockIdx.x);
    } else {
        int b = blockIdx.x - nG;
        for (int e = b * 512 + threadIdx.x; e < ne; e += nF * 512) {
            int t = tgt[e];
            int s = src[e];
            int slot = atomicAdd(&cursor[t], 1);
            csrs[slot] = s;
        }
    }
}

// ---------------- standalone GEMM (layers 2/3) ----------------

__global__ __launch_bounds__(512) void gemm_kernel(const unsigned* __restrict__ A16,
                                                   const unsigned* __restrict__ Bt16,
                                                   const float* __restrict__ dis,
                                                   unsigned short* __restrict__ g8, int n) {
    gemm_body(A16, nullptr, Bt16, dis, g8, n, blockIdx.x);
}

// ---------------- Aggregation (R7 body) ----------------

#define AGG_ACC(v)                                                     \
    { f32x2 p;                                                         \
      p = __builtin_amdgcn_cvt_pk_f32_fp8((int)v.x, 0); f0[0]+=p.x; f1[0]+=p.y; \
      p = __builtin_amdgcn_cvt_pk_f32_fp8((int)v.x, 1); f0[1]+=p.x; f1[1]+=p.y; \
      p = __builtin_amdgcn_cvt_pk_f32_fp8((int)v.y, 0); f0[2]+=p.x; f1[2]+=p.y; \
      p = __builtin_amdgcn_cvt_pk_f32_fp8((int)v.y, 1); f0[3]+=p.x; f1[3]+=p.y; \
      p = __builtin_amdgcn_cvt_pk_f32_fp8((int)v.z, 0); f0[4]+=p.x; f1[4]+=p.y; \
      p = __builtin_amdgcn_cvt_pk_f32_fp8((int)v.z, 1); f0[5]+=p.x; f1[5]+=p.y; \
      p = __builtin_amdgcn_cvt_pk_f32_fp8((int)v.w, 0); f0[6]+=p.x; f1[6]+=p.y; \
      p = __builtin_amdgcn_cvt_pk_f32_fp8((int)v.w, 1); f0[7]+=p.x; f1[7]+=p.y; }

#define ISSUE1(buf, ereg, EBASE, mlim)                                 \
    { int e = (EBASE) + j;                                             \
      int s = __shfl(ereg, e);                                         \
      if (e >= (mlim)) s = n;                                          \
      buf = *(const uint4*)(g8 + (size_t)(unsigned)s * 64u + c * 8); }

#define ROUND4(ereg, Q0, mlim)                                         \
    { uint4 u0, u1, u2, u3;                                            \
      ISSUE1(u0, ereg, (Q0) + 0, mlim)                                 \
      if ((mlim) > (Q0) + 8)  ISSUE1(u1, ereg, (Q0) + 8,  mlim)        \
      if ((mlim) > (Q0) + 16) ISSUE1(u2, ereg, (Q0) + 16, mlim)        \
      if ((mlim) > (Q0) + 24) ISSUE1(u3, ereg, (Q0) + 24, mlim)        \
      AGG_ACC(u0)                                                      \
      if ((mlim) > (Q0) + 8)  AGG_ACC(u1)                              \
      if ((mlim) > (Q0) + 16) AGG_ACC(u2)                              \
      if ((mlim) > (Q0) + 24) AGG_ACC(u3) }

__device__ __forceinline__ void agg_body(const unsigned short* __restrict__ g8,
                                         const float* __restrict__ dis,
                                         const int* __restrict__ rowptr,
                                         const int* __restrict__ csrs,
                                         const float* __restrict__ bias,
                                         unsigned* __restrict__ out16,   // may be null
                                         float* __restrict__ poolseg,
                                         float* lpool, int n) {
    int tid = threadIdx.x;
    if (tid < 128) lpool[tid] = 0.f;
    __syncthreads();

    int wave = tid >> 6, lane = tid & 63;
    int j = lane >> 3;       // edge slot
    int c = lane & 7;        // 16B chunk of the 128B row
    int node0 = (blockIdx.x * 8 + wave) * 4;

    float b0[8], b1[8];
    *(float4*)&b0[0] = *(const float4*)(bias + c * 8);
    *(float4*)&b0[4] = *(const float4*)(bias + c * 8 + 4);
    *(float4*)&b1[0] = *(const float4*)(bias + 64 + c * 8);
    *(float4*)&b1[4] = *(const float4*)(bias + 64 + c * 8 + 4);

    int rpv = 0; float dv = 0.f;
    if (lane <= 4) rpv = rowptr[min(node0 + lane, n)];
    if (lane < 4)  dv  = dis[min(node0 + lane, n - 1)];

    int er[4];
    #pragma unroll
    for (int i = 0; i < 4; i++) {
        int beg = __shfl(rpv, i);
        er[i] = csrs[beg + lane];                  // csrs padded by 64
    }

    uint4 c0, c1, c2, c3, sB;
    {
        int deg = __shfl(rpv, 1) - __shfl(rpv, 0);
        int mlim = min(deg, 64);
        int ereg = er[0];
        ISSUE1(c0, ereg, 0, mlim)
        if (deg > 8)  ISSUE1(c1, ereg, 8,  mlim)
        if (deg > 16) ISSUE1(c2, ereg, 16, mlim)
        if (deg > 24) ISSUE1(c3, ereg, 24, mlim)
        int s = (node0 < n && j == 0) ? node0 : n;
        sB = *(const uint4*)(g8 + (size_t)(unsigned)s * 64u + c * 8);
    }

    float pp0[8] = {}, pp1[8] = {};

    #pragma unroll
    for (int i = 0; i < 4; i++) {
        int node = node0 + i;
        bool ok = node < n;
        int beg = __shfl(rpv, i);
        int end = __shfl(rpv, i + 1);
        int deg = end - beg;
        float di = __shfl(dv, i);

        float f0[8] = {}, f1[8] = {};
        AGG_ACC(c0)
        if (deg > 8)  AGG_ACC(c1)
        if (deg > 16) AGG_ACC(c2)
        if (deg > 24) AGG_ACC(c3)
        if (deg > 32) {
            int mlim = min(deg, 64);
            ROUND4(er[i], 32, mlim)
            for (int b2 = 64; b2 < deg; b2 += 64) {
                int ereg2 = csrs[beg + b2 + lane];
                int ml2 = min(deg - b2, 64);
                ROUND4(ereg2, 0, ml2)
                if (ml2 > 32) ROUND4(ereg2, 32, ml2)
            }
        }

        uint4 n0v, n1v, n2v, n3v, nS;
        if (i < 3) {
            int nd = __shfl(rpv, i + 2) - end;
            int nml = min(nd, 64);
            int ner = er[i + 1];
            ISSUE1(n0v, ner, 0, nml)
            if (nd > 8)  ISSUE1(n1v, ner, 8,  nml)
            if (nd > 16) ISSUE1(n2v, ner, 16, nml)
            if (nd > 24) ISSUE1(n3v, ner, 24, nml)
            int s = (node + 1 < n && j == 0) ? (node + 1) : n;
            nS = *(const uint4*)(g8 + (size_t)(unsigned)s * 64u + c * 8);
        }

        #pragma unroll
        for (int k = 0; k < 8; k++) {
            f0[k] += __shfl_xor(f0[k], 8);  f1[k] += __shfl_xor(f1[k], 8);
            f0[k] += __shfl_xor(f0[k], 16); f1[k] += __shfl_xor(f1[k], 16);
            f0[k] += __shfl_xor(f0[k], 32); f1[k] += __shfl_xor(f1[k], 32);
        }
        if (j == 0) AGG_ACC(sB)

        if (ok) {
            float r0[8], r1[8];
            #pragma unroll
            for (int k = 0; k < 8; k++) {
                r0[k] = fmaxf(di * f0[k] + b0[k], 0.f);
                r1[k] = fmaxf(di * f1[k] + b1[k], 0.f);
                pp0[k] += r0[k];
                pp1[k] += r1[k];
            }
            if (out16 && j == 0) {
                uint4 wa, wb;
                wa.x = cvt_bf16(r0[0]) | (cvt_bf16(r1[0]) << 16);
                wa.y = cvt_bf16(r0[1]) | (cvt_bf16(r1[1]) << 16);
                wa.z = cvt_bf16(r0[2]) | (cvt_bf16(r1[2]) << 16);
                wa.w = cvt_bf16(r0[3]) | (cvt_bf16(r1[3]) << 16);
                wb.x = cvt_bf16(r0[4]) | (cvt_bf16(r1[4]) << 16);
                wb.y = cvt_bf16(r0[5]) | (cvt_bf16(r1[5]) << 16);
                wb.z = cvt_bf16(r0[6]) | (cvt_bf16(r1[6]) << 16);
                wb.w = cvt_bf16(r0[7]) | (cvt_bf16(r1[7]) << 16);
                *(uint4*)(out16 + (size_t)node * 64 + c * 8)     = wa;
                *(uint4*)(out16 + (size_t)node * 64 + c * 8 + 4) = wb;
            }
        }
        c0 = n0v; c1 = n1v; c2 = n2v; c3 = n3v; sB = nS;
    }

    if (j == 0) {
        #pragma unroll
        for (int k = 0; k < 8; k++) {
            atomicAdd(&lpool[c * 8 + k],      pp0[k]);
            atomicAdd(&lpool[64 + c * 8 + k], pp1[k]);
        }
    }
    __syncthreads();
    if (tid < 128) atomicAdd(&poolseg[tid], lpool[tid]);
}

__global__ __launch_bounds__(512) void agg_kernel(const unsigned short* __restrict__ g8,
                                                  const float* __restrict__ dis,
                                                  const int* __restrict__ rowptr,
                                                  const int* __restrict__ csrs,
                                                  const float* __restrict__ bias,
                                                  unsigned* __restrict__ out16,
                                                  float* __restrict__ poolseg, int n) {
    __shared__ float lpool[128];
    agg_body(g8, dis, rowptr, csrs, bias, out16, poolseg, lpool, n);
}

// agg layer 3 + MLP head fused (last-block pattern)
__global__ __launch_bounds__(512) void aggmlp_kernel(const unsigned short* __restrict__ g8,
                                                     const float* __restrict__ dis,
                                                     const int* __restrict__ rowptr,
                                                     const int* __restrict__ csrs,
                                                     const float* __restrict__ bias,
                                                     float* __restrict__ pool,
                                                     int* __restrict__ ctrs,
                                                     const float* __restrict__ fw1, const float* __restrict__ fb1,
                                                     const float* __restrict__ fw2, const float* __restrict__ fb2,
                                                     const float* __restrict__ fw3, const float* __restrict__ fb3,
                                                     float* __restrict__ out, int n) {
    __shared__ float lpool[128];
    __shared__ float h0[384];
    __shared__ float h1[128];
    __shared__ float h2[64];
    __shared__ int slast;

    agg_body(g8, dis, rowptr, csrs, bias, (unsigned*)nullptr, pool + 256, lpool, n);

    int tid = threadIdx.x;
    if (tid == 0) {
        __threadfence();
        int old = atomicAdd(&ctrs[2], 1);
        slast = (old == (int)gridDim.x - 1) ? 1 : 0;
    }
    __syncthreads();
    if (!slast) return;

    // last block: all pool atomics device-visible; read with agent-scope atomics
    for (int i = tid; i < 384; i += 512)
        h0[i] = __hip_atomic_load(&pool[i], __ATOMIC_RELAXED, __HIP_MEMORY_SCOPE_AGENT);
    __syncthreads();
    if (tid < 128) {
        float s = fb1[tid];
        for (int k = 0; k < 384; k++) s += h0[k] * fw1[k * 128 + tid];
        h1[tid] = fmaxf(s, 0.f);
    }
    __syncthreads();
    if (tid < 64) {
        float s = fb2[tid];
        for (int k = 0; k < 128; k++) s += h1[k] * fw2[k * 64 + tid];
        h2[tid] = fmaxf(s, 0.f);
    }
    __syncthreads();
    if (tid < 10) {
        float s = fb3[tid];
        for (int k = 0; k < 64; k++) s += h2[k] * fw3[k * 10 + tid];
        out[tid] = s;
    }
}

// ---------------- launch ----------------

extern "C" void kernel_launch(void* const* d_in, const int* in_sizes, int n_in,
                              void* d_out, int out_size, void* d_ws, size_t ws_size,
                              hipStream_t stream) {
    const float* x   = (const float*)d_in[0];
    const int*   ei  = (const int*)d_in[1];
    const float* W1  = (const float*)d_in[2];
    const float* b1  = (const float*)d_in[3];
    const float* W2  = (const float*)d_in[4];
    const float* b2  = (const float*)d_in[5];
    const float* W3  = (const float*)d_in[6];
    const float* b3  = (const float*)d_in[7];
    const float* fw1 = (const float*)d_in[8];
    const float* fb1 = (const float*)d_in[9];
    const float* fw2 = (const float*)d_in[10];
    const float* fb2 = (const float*)d_in[11];
    const float* fw3 = (const float*)d_in[12];
    const float* fb3 = (const float*)d_in[13];
    float* out = (float*)d_out;

    const int n  = in_sizes[0] / FDIM;   // 50000
    const int ne = in_sizes[1] / 2;      // 600000
    const int* src = ei;
    const int* tgt = ei + ne;

    char* ws = (char*)d_ws;
    size_t packBytes = (size_t)n * 64 * sizeof(unsigned);   // 12.8 MB
    unsigned* A2   = (unsigned*)ws;  ws += packBytes;
    unsigned* A3   = (unsigned*)ws;  ws += packBytes;
    unsigned short* g8 = (unsigned short*)ws; ws += (((size_t)(n + 1) * 64 * 2 + 127) / 128) * 128; // 6.4 MB
    unsigned* B1t  = (unsigned*)ws;  ws += 128 * 64 * 4;
    unsigned* B2t  = (unsigned*)ws;  ws += 128 * 64 * 4;
    unsigned* B3t  = (unsigned*)ws;  ws += 128 * 64 * 4;
    float* dis  = (float*)ws;        ws += (size_t)n * 4;
    // contiguous memset zone: count | ctrs(8) | pool(384)
    int* count  = (int*)ws;          ws += (size_t)n * 4;
    int* ctrs   = (int*)ws;          ws += 8 * 4;
    float* pool = (float*)ws;        ws += 384 * 4;
    int* rowptr = (int*)ws;          ws += ((size_t)(n + 4) * 4 / 16) * 16;
    int* cursor = (int*)ws;          ws += (size_t)n * 4;
    int* csrs   = (int*)ws;          ws += (size_t)(ne + 64) * 4;   // +64 pad for prefetch
    int* bsum   = (int*)ws;          ws += 32 * 4;
    int* bpre   = (int*)ws;          ws += 32 * 4;

    // one memset node covers count + ctrs + pool
    hipMemsetAsync(count, 0, (size_t)(n + 8 + 384) * 4, stream);

    // prep + hist fused
    int phTotal = 24640 + ne;
    prephist_kernel<<<(phTotal + 255) / 256, 256, 0, stream>>>(W1, W2, W3, B1t, B2t, B3t,
                                                               g8, tgt, count, n, ne);

    // single-dispatch scan (dis + rowptr + cursor)
    int nb = (n + 2047) / 2048;                  // 25
    scan_kernel<<<nb, 256, 0, stream>>>(count, dis, rowptr, cursor, bsum, bpre, ctrs, n, nb);

    // fill + gemm1 fused
    int nG = (n + 127) / 128;                    // gemm blocks (512 thr, 128 rows)
    int nF = 128;                                // fill blocks
    fillgemm_kernel<<<nG + nF, 512, 0, stream>>>(src, tgt, cursor, csrs, x, B1t, dis, g8,
                                                 n, ne, nG, nF);

    int aggGrid = (n + 31) / 32;

    agg_kernel<<<aggGrid, 512, 0, stream>>>(g8, dis, rowptr, csrs, b1, A2, pool + 0, n);
    gemm_kernel<<<nG, 512, 0, stream>>>(A2, B2t, dis, g8, n);
    agg_kernel<<<aggGrid, 512, 0, stream>>>(g8, dis, rowptr, csrs, b2, A3, pool + 128, n);
    gemm_kernel<<<nG, 512, 0, stream>>>(A3, B3t, dis, g8, n);
    aggmlp_kernel<<<aggGrid, 512, 0, stream>>>(g8, dis, rowptr, csrs, b3, pool, ctrs,
                                               fw1, fb1, fw2, fb2, fw3, fb3, out, n);
}